// Round 3
// baseline (349.024 us; speedup 1.0000x reference)
//
#include <hip/hip_runtime.h>

#define HH 224
#define WW 224
#define PSD 112
#define NP 12544      // 112*112 patches per plane
#define NBG 1024      // B*G
#define NCH 28        // 4-patch chunks per patch row
#define HROWS 56      // patch rows per half
#define HTASK (HROWS * NCH)   // 1568 tasks per half-plane
#define PSTRIDE 56    // floats per partial record

// upper-triangle index for symmetric 9x9: i<=j
#define MIDX(i, j) (9 * (i) - (i) * ((i)-1) / 2 + ((j) - (i)))

// Load L[0..8] = x[r][8t-1 .. 8t+7] (r assumed >= 0)
__device__ __forceinline__ void load_row9(const float* __restrict__ row,
                                          int t, float* L) {
    const int cb = 8 * t;
    L[0] = (t == 0) ? 0.f : row[cb - 1];
    float4 a = *reinterpret_cast<const float4*>(row + cb);
    float4 b = *reinterpret_cast<const float4*>(row + cb + 4);
    L[1] = a.x; L[2] = a.y; L[3] = a.z; L[4] = a.w;
    L[5] = b.x; L[6] = b.y; L[7] = b.z; L[8] = b.w;
}

// ---------------------------------------------------------------------------
// K1: partial 9x9 gram (45 upper + 9 sums) over half a plane
// ---------------------------------------------------------------------------
__global__ __launch_bounds__(256, 8) void gram_k(const float* __restrict__ x,
                                                 float* __restrict__ partial) {
    const int bg = blockIdx.x;
    const int half = blockIdx.y;
    const float* __restrict__ xp = x + (size_t)bg * (HH * WW);
    const int tid = threadIdx.x;

    float acc[45];
    float sm[9];
#pragma unroll
    for (int k = 0; k < 45; ++k) acc[k] = 0.f;
#pragma unroll
    for (int i = 0; i < 9; ++i) sm[i] = 0.f;

    for (int task = tid; task < HTASK; task += 256) {
        const int phh = task / NCH;
        const int t = task - phh * NCH;
        const int ph = half * HROWS + phh;
        const int r0 = 2 * ph - 1;
        float L[3][9];
#pragma unroll
        for (int kr = 0; kr < 3; ++kr) {
            const int r = r0 + kr;
            if (r < 0) {
#pragma unroll
                for (int j = 0; j < 9; ++j) L[kr][j] = 0.f;
            } else {
                load_row9(xp + r * WW, t, L[kr]);
            }
        }
#pragma unroll
        for (int u = 0; u < 4; ++u) {
            float v[9];
#pragma unroll
            for (int kh = 0; kh < 3; ++kh)
#pragma unroll
                for (int kw = 0; kw < 3; ++kw) v[3 * kh + kw] = L[kh][2 * u + kw];
            int k = 0;
#pragma unroll
            for (int i = 0; i < 9; ++i) {
                sm[i] += v[i];
#pragma unroll
                for (int j = i; j < 9; ++j) {
                    acc[k] += v[i] * v[j];
                    ++k;
                }
            }
        }
    }

    __shared__ float red[4][56];
    const int lane = tid & 63;
    const int wv = tid >> 6;
#pragma unroll
    for (int k = 0; k < 45; ++k) {
        float v = acc[k];
#pragma unroll
        for (int off = 32; off; off >>= 1) v += __shfl_down(v, off, 64);
        if (lane == 0) red[wv][k] = v;
    }
#pragma unroll
    for (int i = 0; i < 9; ++i) {
        float v = sm[i];
#pragma unroll
        for (int off = 32; off; off >>= 1) v += __shfl_down(v, off, 64);
        if (lane == 0) red[wv][45 + i] = v;
    }
    __syncthreads();
    if (tid < 54) {
        float s = red[0][tid] + red[1][tid] + red[2][tid] + red[3][tid];
        partial[(size_t)(bg * 2 + half) * PSTRIDE + tid] = s;
    }
}

// ---------------------------------------------------------------------------
// K2: per-(b,g) energy -> softmax -> effective 9-tap filter + bias
// ---------------------------------------------------------------------------
__global__ __launch_bounds__(256) void solve_k(
    const float* __restrict__ Wq, const float* __restrict__ bq,
    const float* __restrict__ Wk, const float* __restrict__ bk,
    const float* __restrict__ Wv, const float* __restrict__ bv,
    const float* __restrict__ Wo, const float* __restrict__ bo,
    const float* __restrict__ partial, float* __restrict__ cd) {
    const int bg = blockIdx.x * 256 + threadIdx.x;
    if (bg >= NBG) return;
    const int g = bg & 63;

    const float* pa = partial + (size_t)bg * 2 * PSTRIDE;
    float gp[54];
#pragma unroll
    for (int k = 0; k < 54; ++k) gp[k] = pa[k] + pa[PSTRIDE + k];

    float M[9][9];
    {
        int k = 0;
#pragma unroll
        for (int i = 0; i < 9; ++i)
#pragma unroll
            for (int j = i; j < 9; ++j) {
                float v = gp[k++];
                M[i][j] = v;
                M[j][i] = v;
            }
    }
    float m[9];
#pragma unroll
    for (int i = 0; i < 9; ++i) m[i] = gp[45 + i];

    const float* wq = Wq + g * 81;
    const float* wk = Wk + g * 81;
    const float* bqg = bq + g * 9;
    const float* bkg = bk + g * 9;

    float Qm[9];
#pragma unroll
    for (int t = 0; t < 9; ++t) {
        float s = 0.f;
#pragma unroll
        for (int j = 0; j < 9; ++j) s += wq[t * 9 + j] * m[j];
        Qm[t] = s;
    }
    float T[9][9];
#pragma unroll
    for (int i = 0; i < 9; ++i)
#pragma unroll
        for (int t = 0; t < 9; ++t) {
            float s = 0.f;
#pragma unroll
            for (int j = 0; j < 9; ++j) s += M[i][j] * wq[t * 9 + j];
            T[i][t] = s;
        }

    const float* wog = Wo + g * 9;
    float weff[9];
#pragma unroll
    for (int t = 0; t < 9; ++t) weff[t] = 0.f;

#pragma unroll
    for (int s = 0; s < 9; ++s) {
        float Km_s = 0.f;
#pragma unroll
        for (int i = 0; i < 9; ++i) Km_s += wk[s * 9 + i] * m[i];
        const float bks = bkg[s];
        float e[9];
#pragma unroll
        for (int t = 0; t < 9; ++t) {
            float sum = bks * Qm[t] + bqg[t] * Km_s + 12544.f * bks * bqg[t];
#pragma unroll
            for (int i = 0; i < 9; ++i) sum += wk[s * 9 + i] * T[i][t];
            e[t] = sum;
        }
        float mx = e[0];
#pragma unroll
        for (int t = 1; t < 9; ++t) mx = fmaxf(mx, e[t]);
        float ex[9], se = 0.f;
#pragma unroll
        for (int t = 0; t < 9; ++t) {
            ex[t] = expf(e[t] - mx);
            se += ex[t];
        }
        const float wos = wog[s] / se;
#pragma unroll
        for (int t = 0; t < 9; ++t) weff[t] += wos * ex[t];
    }

    const float* wv = Wv + g * 81;
    const float* bvg = bv + g * 9;
    float* o = cd + (size_t)bg * 16;
    float d = bo[g];
#pragma unroll
    for (int j = 0; j < 9; ++j) {
        float s = 0.f;
#pragma unroll
        for (int t = 0; t < 9; ++t) s += weff[t] * wv[t * 9 + j];
        o[j] = s;
    }
#pragma unroll
    for (int t = 0; t < 9; ++t) d += weff[t] * bvg[t];
    o[9] = d;
}

// ---------------------------------------------------------------------------
// K3: 3x3 stride-2 conv with per-(b,g) taps over half a plane
// ---------------------------------------------------------------------------
__global__ __launch_bounds__(256, 8) void conv_k(const float* __restrict__ x,
                                                 const float* __restrict__ cd,
                                                 float* __restrict__ out) {
    const int bg = blockIdx.x;
    const int half = blockIdx.y;
    const float* __restrict__ xp = x + (size_t)bg * (HH * WW);
    const float* cp = cd + (size_t)bg * 16;
    float cc[9];
#pragma unroll
    for (int j = 0; j < 9; ++j) cc[j] = cp[j];
    const float dd = cp[9];
    float* __restrict__ op = out + (size_t)bg * NP;
    const int tid = threadIdx.x;

    for (int task = tid; task < HTASK; task += 256) {
        const int phh = task / NCH;
        const int t = task - phh * NCH;
        const int ph = half * HROWS + phh;
        const int r0 = 2 * ph - 1;
        float L[3][9];
#pragma unroll
        for (int kr = 0; kr < 3; ++kr) {
            const int r = r0 + kr;
            if (r < 0) {
#pragma unroll
                for (int j = 0; j < 9; ++j) L[kr][j] = 0.f;
            } else {
                load_row9(xp + r * WW, t, L[kr]);
            }
        }
        float o[4];
#pragma unroll
        for (int u = 0; u < 4; ++u) {
            float s = dd;
#pragma unroll
            for (int kh = 0; kh < 3; ++kh)
#pragma unroll
                for (int kw = 0; kw < 3; ++kw)
                    s += cc[3 * kh + kw] * L[kh][2 * u + kw];
            o[u] = s;
        }
        *reinterpret_cast<float4*>(op + ph * PSD + 4 * t) =
            make_float4(o[0], o[1], o[2], o[3]);
    }
}

extern "C" void kernel_launch(void* const* d_in, const int* in_sizes, int n_in,
                              void* d_out, int out_size, void* d_ws, size_t ws_size,
                              hipStream_t stream) {
    const float* x = (const float*)d_in[0];
    const float* Wq = (const float*)d_in[1];
    const float* bq = (const float*)d_in[2];
    const float* Wk = (const float*)d_in[3];
    const float* bk = (const float*)d_in[4];
    const float* Wv = (const float*)d_in[5];
    const float* bv = (const float*)d_in[6];
    const float* Wo = (const float*)d_in[7];
    const float* bo = (const float*)d_in[8];
    float* out = (float*)d_out;

    float* partial = (float*)d_ws;                    // 2048 * 56 floats
    float* cd = partial + (size_t)NBG * 2 * PSTRIDE;  // 1024 * 16 floats

    gram_k<<<dim3(NBG, 2), 256, 0, stream>>>(x, partial);
    solve_k<<<4, 256, 0, stream>>>(Wq, bq, Wk, bk, Wv, bv, Wo, bo, partial, cd);
    conv_k<<<dim3(NBG, 2), 256, 0, stream>>>(x, cd, out);
}

// Round 4
// 121.444 us; speedup vs baseline: 2.8740x; 2.8740x over previous
//
#include <hip/hip_runtime.h>

#define HH 224
#define WW 224
#define PSD 112
#define NP 12544      // 112*112 patches per plane
#define NBG 1024      // B*G
#define NCH 28        // 4-patch chunks per patch row
#define HROWS 56      // patch rows per half
#define HTASK (HROWS * NCH)   // 1568 tasks per half-plane
#define PSTRIDE 56    // floats per partial record

// Load L[0..8] = x[r][8t-1 .. 8t+7] (r assumed >= 0)
__device__ __forceinline__ void load_row9(const float* __restrict__ row,
                                          int t, float* L) {
    const int cb = 8 * t;
    L[0] = (t == 0) ? 0.f : row[cb - 1];
    float4 a = *reinterpret_cast<const float4*>(row + cb);
    float4 b = *reinterpret_cast<const float4*>(row + cb + 4);
    L[1] = a.x; L[2] = a.y; L[3] = a.z; L[4] = a.w;
    L[5] = b.x; L[6] = b.y; L[7] = b.z; L[8] = b.w;
}

// ---------------------------------------------------------------------------
// K1: partial 9x9 gram (45 upper + 9 sums) over half a plane
// launch_bounds(256,4): allows up to 128 VGPR; compiler lands at 64 (proven in
// round 2) -> HW schedules 8 blocks/CU. (256,8) forces 32 VGPR -> spills!
// ---------------------------------------------------------------------------
__global__ __launch_bounds__(256, 4) void gram_k(const float* __restrict__ x,
                                                 float* __restrict__ partial) {
    const int bg = blockIdx.x;
    const int half = blockIdx.y;
    const float* __restrict__ xp = x + (size_t)bg * (HH * WW);
    const int tid = threadIdx.x;

    float acc[45];
    float sm[9];
#pragma unroll
    for (int k = 0; k < 45; ++k) acc[k] = 0.f;
#pragma unroll
    for (int i = 0; i < 9; ++i) sm[i] = 0.f;

    for (int task = tid; task < HTASK; task += 256) {
        const int phh = task / NCH;
        const int t = task - phh * NCH;
        const int ph = half * HROWS + phh;
        const int r0 = 2 * ph - 1;
        float L[3][9];
#pragma unroll
        for (int kr = 0; kr < 3; ++kr) {
            const int r = r0 + kr;
            if (r < 0) {
#pragma unroll
                for (int j = 0; j < 9; ++j) L[kr][j] = 0.f;
            } else {
                load_row9(xp + r * WW, t, L[kr]);
            }
        }
#pragma unroll
        for (int u = 0; u < 4; ++u) {
            float v[9];
#pragma unroll
            for (int kh = 0; kh < 3; ++kh)
#pragma unroll
                for (int kw = 0; kw < 3; ++kw) v[3 * kh + kw] = L[kh][2 * u + kw];
            int k = 0;
#pragma unroll
            for (int i = 0; i < 9; ++i) {
                sm[i] += v[i];
#pragma unroll
                for (int j = i; j < 9; ++j) {
                    acc[k] += v[i] * v[j];
                    ++k;
                }
            }
        }
    }

    __shared__ float red[4][56];
    const int lane = tid & 63;
    const int wv = tid >> 6;
#pragma unroll
    for (int k = 0; k < 45; ++k) {
        float v = acc[k];
#pragma unroll
        for (int off = 32; off; off >>= 1) v += __shfl_down(v, off, 64);
        if (lane == 0) red[wv][k] = v;
    }
#pragma unroll
    for (int i = 0; i < 9; ++i) {
        float v = sm[i];
#pragma unroll
        for (int off = 32; off; off >>= 1) v += __shfl_down(v, off, 64);
        if (lane == 0) red[wv][45 + i] = v;
    }
    __syncthreads();
    if (tid < 54) {
        float s = red[0][tid] + red[1][tid] + red[2][tid] + red[3][tid];
        partial[(size_t)(bg * 2 + half) * PSTRIDE + tid] = s;
    }
}

// ---------------------------------------------------------------------------
// K2: per-(b,g) energy -> softmax -> effective 9-tap filter + bias
// ---------------------------------------------------------------------------
__global__ __launch_bounds__(256) void solve_k(
    const float* __restrict__ Wq, const float* __restrict__ bq,
    const float* __restrict__ Wk, const float* __restrict__ bk,
    const float* __restrict__ Wv, const float* __restrict__ bv,
    const float* __restrict__ Wo, const float* __restrict__ bo,
    const float* __restrict__ partial, float* __restrict__ cd) {
    const int bg = blockIdx.x * 256 + threadIdx.x;
    if (bg >= NBG) return;
    const int g = bg & 63;

    const float* pa = partial + (size_t)bg * 2 * PSTRIDE;
    float gp[54];
#pragma unroll
    for (int k = 0; k < 54; ++k) gp[k] = pa[k] + pa[PSTRIDE + k];

    float M[9][9];
    {
        int k = 0;
#pragma unroll
        for (int i = 0; i < 9; ++i)
#pragma unroll
            for (int j = i; j < 9; ++j) {
                float v = gp[k++];
                M[i][j] = v;
                M[j][i] = v;
            }
    }
    float m[9];
#pragma unroll
    for (int i = 0; i < 9; ++i) m[i] = gp[45 + i];

    const float* wq = Wq + g * 81;
    const float* wk = Wk + g * 81;
    const float* bqg = bq + g * 9;
    const float* bkg = bk + g * 9;

    float Qm[9];
#pragma unroll
    for (int t = 0; t < 9; ++t) {
        float s = 0.f;
#pragma unroll
        for (int j = 0; j < 9; ++j) s += wq[t * 9 + j] * m[j];
        Qm[t] = s;
    }
    float T[9][9];
#pragma unroll
    for (int i = 0; i < 9; ++i)
#pragma unroll
        for (int t = 0; t < 9; ++t) {
            float s = 0.f;
#pragma unroll
            for (int j = 0; j < 9; ++j) s += M[i][j] * wq[t * 9 + j];
            T[i][t] = s;
        }

    const float* wog = Wo + g * 9;
    float weff[9];
#pragma unroll
    for (int t = 0; t < 9; ++t) weff[t] = 0.f;

#pragma unroll
    for (int s = 0; s < 9; ++s) {
        float Km_s = 0.f;
#pragma unroll
        for (int i = 0; i < 9; ++i) Km_s += wk[s * 9 + i] * m[i];
        const float bks = bkg[s];
        float e[9];
#pragma unroll
        for (int t = 0; t < 9; ++t) {
            float sum = bks * Qm[t] + bqg[t] * Km_s + 12544.f * bks * bqg[t];
#pragma unroll
            for (int i = 0; i < 9; ++i) sum += wk[s * 9 + i] * T[i][t];
            e[t] = sum;
        }
        float mx = e[0];
#pragma unroll
        for (int t = 1; t < 9; ++t) mx = fmaxf(mx, e[t]);
        float ex[9], se = 0.f;
#pragma unroll
        for (int t = 0; t < 9; ++t) {
            ex[t] = expf(e[t] - mx);
            se += ex[t];
        }
        const float wos = wog[s] / se;
#pragma unroll
        for (int t = 0; t < 9; ++t) weff[t] += wos * ex[t];
    }

    const float* wv = Wv + g * 81;
    const float* bvg = bv + g * 9;
    float* o = cd + (size_t)bg * 16;
    float d = bo[g];
#pragma unroll
    for (int j = 0; j < 9; ++j) {
        float s = 0.f;
#pragma unroll
        for (int t = 0; t < 9; ++t) s += weff[t] * wv[t * 9 + j];
        o[j] = s;
    }
#pragma unroll
    for (int t = 0; t < 9; ++t) d += weff[t] * bvg[t];
    o[9] = d;
}

// ---------------------------------------------------------------------------
// K3: 3x3 stride-2 conv with per-(b,g) taps over half a plane
// ---------------------------------------------------------------------------
__global__ __launch_bounds__(256, 4) void conv_k(const float* __restrict__ x,
                                                 const float* __restrict__ cd,
                                                 float* __restrict__ out) {
    const int bg = blockIdx.x;
    const int half = blockIdx.y;
    const float* __restrict__ xp = x + (size_t)bg * (HH * WW);
    const float* cp = cd + (size_t)bg * 16;
    float cc[9];
#pragma unroll
    for (int j = 0; j < 9; ++j) cc[j] = cp[j];
    const float dd = cp[9];
    float* __restrict__ op = out + (size_t)bg * NP;
    const int tid = threadIdx.x;

    for (int task = tid; task < HTASK; task += 256) {
        const int phh = task / NCH;
        const int t = task - phh * NCH;
        const int ph = half * HROWS + phh;
        const int r0 = 2 * ph - 1;
        float L[3][9];
#pragma unroll
        for (int kr = 0; kr < 3; ++kr) {
            const int r = r0 + kr;
            if (r < 0) {
#pragma unroll
                for (int j = 0; j < 9; ++j) L[kr][j] = 0.f;
            } else {
                load_row9(xp + r * WW, t, L[kr]);
            }
        }
        float o[4];
#pragma unroll
        for (int u = 0; u < 4; ++u) {
            float s = dd;
#pragma unroll
            for (int kh = 0; kh < 3; ++kh)
#pragma unroll
                for (int kw = 0; kw < 3; ++kw)
                    s += cc[3 * kh + kw] * L[kh][2 * u + kw];
            o[u] = s;
        }
        *reinterpret_cast<float4*>(op + ph * PSD + 4 * t) =
            make_float4(o[0], o[1], o[2], o[3]);
    }
}

extern "C" void kernel_launch(void* const* d_in, const int* in_sizes, int n_in,
                              void* d_out, int out_size, void* d_ws, size_t ws_size,
                              hipStream_t stream) {
    const float* x = (const float*)d_in[0];
    const float* Wq = (const float*)d_in[1];
    const float* bq = (const float*)d_in[2];
    const float* Wk = (const float*)d_in[3];
    const float* bk = (const float*)d_in[4];
    const float* Wv = (const float*)d_in[5];
    const float* bv = (const float*)d_in[6];
    const float* Wo = (const float*)d_in[7];
    const float* bo = (const float*)d_in[8];
    float* out = (float*)d_out;

    float* partial = (float*)d_ws;                    // 2048 * 56 floats
    float* cd = partial + (size_t)NBG * 2 * PSTRIDE;  // 1024 * 16 floats

    gram_k<<<dim3(NBG, 2), 256, 0, stream>>>(x, partial);
    solve_k<<<4, 256, 0, stream>>>(Wq, bq, Wk, bk, Wv, bv, Wo, bo, partial, cd);
    conv_k<<<dim3(NBG, 2), 256, 0, stream>>>(x, cd, out);
}